// Round 1
// baseline (172.567 us; speedup 1.0000x reference)
//
#include <hip/hip_runtime.h>
#include <math.h>

#define MAXR 100.0f
// B=4, C=64, H=64, W=64 fixed per setup_inputs()

// ---------------- Kernel 1: 3x3 conv (C=64 -> 2) + 100*tanh -> alpha, beta ---
__global__ void conv_ab(const float* __restrict__ x, const float* __restrict__ w,
                        const float* __restrict__ bias,
                        float* __restrict__ alpha, float* __restrict__ beta) {
    int p = blockIdx.x * blockDim.x + threadIdx.x;   // pixel id over B*H*W = 16384
    if (p >= 4 * 64 * 64) return;
    int wpos = p & 63;
    int hpos = (p >> 6) & 63;
    int b    = p >> 12;
    const float* xb = x + b * (64 * 64 * 64);
    float acc0 = bias[0], acc1 = bias[1];
    for (int c = 0; c < 64; ++c) {
        const float* xc = xb + c * 4096;
        const float* w0 = w + c * 9;          // out channel 0 (alpha)
        const float* w1 = w + 576 + c * 9;    // out channel 1 (beta)
        #pragma unroll
        for (int kh = 0; kh < 3; ++kh) {
            int hh = hpos + kh - 1;
            if (hh < 0 || hh > 63) continue;   // wave-uniform (wave = one h row)
            #pragma unroll
            for (int kw = 0; kw < 3; ++kw) {
                int ww = wpos + kw - 1;
                if (ww < 0 || ww > 63) continue;
                float xv = xc[hh * 64 + ww];
                acc0 = fmaf(xv, w0[kh * 3 + kw], acc0);
                acc1 = fmaf(xv, w1[kh * 3 + kw], acc1);
            }
        }
    }
    alpha[p] = MAXR * tanhf(acc0);
    beta[p]  = MAXR * tanhf(acc1);
}

// ---------------- Kernel 2: per-pixel pairwise soft-abs + softmax + weighted sum
// Block = 256 threads = 4 waves; handles 16 consecutive-w pixels (same b,h).
// Wave = one pixel at a time (4 each); lane = channel j.
__global__ __launch_bounds__(256) void dsf_main(const float* __restrict__ x,
                                                const float* __restrict__ alpha_g,
                                                const float* __restrict__ beta_g,
                                                float* __restrict__ out) {
    __shared__ float xs[64 * 17];             // [c][w-tile], stride 17 kills bank conflicts
    int tile = blockIdx.x;                    // 1024 tiles
    int p0   = tile * 16;                     // first pixel of tile (same b,h row)
    int b    = p0 >> 12;
    const float* xb = x + b * (64 * 64 * 64) + (p0 & 4095);   // + h*64 + w0

    // stage 64c x 16w tile, coalesced in 64B runs
    for (int e = threadIdx.x; e < 1024; e += 256) {
        int c = e >> 4, wl = e & 15;
        xs[c * 17 + wl] = xb[c * 4096 + wl];
    }
    __syncthreads();

    int lane = threadIdx.x & 63;
    int wave = threadIdx.x >> 6;

    for (int k = 0; k < 4; ++k) {
        int wl = wave * 4 + k;
        int p  = p0 + wl;
        float al   = alpha_g[p];
        float be   = beta_g[p];
        float aa   = fabsf(al);
        float n2aa = -2.0f * aa;              // exp(-2*min(aa*ad,100)) = exp(max(n2aa*ad,-200))
        float xj   = xs[lane * 17 + wl];      // x[b, lane, h, w]

        float A = 0.0f;
        #pragma unroll 8
        for (int i = 0; i < 64; ++i) {
            float xi = __shfl(xj, i, 64);                 // x_i broadcast from lane i
            float dd = fmaf(be, xi, -xj);                 // beta*x_i - x_j
            float ad = fabsf(dd);
            float e2 = __expf(fmaxf(n2aa * ad, -200.0f)); // exp(-2*clip)
            // tanh(clip) = (1-e2)/(1+e2), fast rcp (~1 ulp, well within 3.9e-2 budget)
            float t  = (1.0f - e2) * __builtin_amdgcn_rcpf(1.0f + e2);
            A = fmaf(ad, t, A);                           // += |d| * tanh(|alpha||d| clipped)
        }

        // logits: g_j = clip(-tmp_j*alpha) = max(-A*|alpha|/64, -100)   (sign(alpha) cancels)
        float g = fmaxf(-A * aa * (1.0f / 64.0f), -MAXR);

        float gm = g;
        #pragma unroll
        for (int off = 32; off; off >>= 1) gm = fmaxf(gm, __shfl_xor(gm, off, 64));
        float ew  = __expf(g - gm);
        float den = ew, num = xj * ew;
        #pragma unroll
        for (int off = 32; off; off >>= 1) {
            den += __shfl_xor(den, off, 64);
            num += __shfl_xor(num, off, 64);
        }
        if (lane == 0) out[p] = num / den;
    }
}

extern "C" void kernel_launch(void* const* d_in, const int* in_sizes, int n_in,
                              void* d_out, int out_size, void* d_ws, size_t ws_size,
                              hipStream_t stream) {
    const float* x      = (const float*)d_in[0];   // (4,64,64,64)
    const float* conv_w = (const float*)d_in[1];   // (2,64,3,3)
    const float* conv_b = (const float*)d_in[2];   // (2,)
    float* out   = (float*)d_out;                  // (4,1,64,64) = 16384 floats
    float* alpha = (float*)d_ws;                   // 16384 floats
    float* beta  = alpha + 16384;                  // 16384 floats

    conv_ab<<<64, 256, 0, stream>>>(x, conv_w, conv_b, alpha, beta);
    dsf_main<<<1024, 256, 0, stream>>>(x, alpha, beta, out);
}

// Round 2
// 95.549 us; speedup vs baseline: 1.8061x; 1.8061x over previous
//
#include <hip/hip_runtime.h>
#include <math.h>

#define MAXR 100.0f
// B=4, C=64, H=64, W=64 fixed per setup_inputs()

// ---------------- Kernel 1: 3x3 conv (C=64 -> 2) + 100*tanh -> alpha, beta ---
// One block per (b,h) row. 256 threads = 4 waves; lane = pixel w; wave g owns
// channels 16g..16g+15. x 3-row slab + weights staged in LDS.
__global__ __launch_bounds__(256) void conv_ab(const float* __restrict__ x,
                                               const float* __restrict__ w,
                                               const float* __restrict__ bias,
                                               float* __restrict__ alpha,
                                               float* __restrict__ beta) {
    __shared__ float xs[64 * 3 * 64];   // [c][r][w]  48 KB
    __shared__ float wl[1152];          // [oc][c][3][3]  4.6 KB
    __shared__ float red[4][2][64];     // per-wave partials

    int row = blockIdx.x;               // b*64 + h
    int b = row >> 6, h = row & 63;
    int tid = threadIdx.x;
    int lane = tid & 63, g = tid >> 6;
    int l4 = lane & 15, quad = lane >> 4;

    // stage weights (coalesced)
    for (int e = tid; e < 1152; e += 256) wl[e] = w[e];

    // stage x[b, :, h-1:h+2, :]: 192 (r,c) rows, 16 rows per block-iteration,
    // each quad of 16 lanes loads one 64-float row as float4s. Zeros for OOB h.
    const float* xb = x + b * 262144;
    for (int pair = g * 4 + quad; pair < 192; pair += 16) {
        int r = pair >> 6, c = pair & 63;     // r in 0..2, c in 0..63
        int hh = h + r - 1;
        float4 v = make_float4(0.f, 0.f, 0.f, 0.f);
        if (hh >= 0 && hh < 64)
            v = *(const float4*)(xb + c * 4096 + hh * 64 + l4 * 4);
        *(float4*)(xs + c * 192 + r * 64 + l4 * 4) = v;
    }
    __syncthreads();

    // compute: lane = pixel w, accumulate 16 channels x 9 taps for both outputs
    float a0 = 0.f, a1 = 0.f;
    bool mL = (lane >= 1), mR = (lane <= 62);
    for (int cc = 0; cc < 16; ++cc) {
        int c = (g << 4) + cc;
        const float* xc = xs + c * 192;
        const float* w0 = wl + c * 9;
        const float* w1 = wl + 576 + c * 9;
        #pragma unroll
        for (int r = 0; r < 3; ++r) {
            float xm = mL ? xc[r * 64 + lane - 1] : 0.f;
            float x0 = xc[r * 64 + lane];
            float xp = mR ? xc[r * 64 + lane + 1] : 0.f;
            a0 = fmaf(xm, w0[r * 3 + 0], a0);
            a0 = fmaf(x0, w0[r * 3 + 1], a0);
            a0 = fmaf(xp, w0[r * 3 + 2], a0);
            a1 = fmaf(xm, w1[r * 3 + 0], a1);
            a1 = fmaf(x0, w1[r * 3 + 1], a1);
            a1 = fmaf(xp, w1[r * 3 + 2], a1);
        }
    }
    red[g][0][lane] = a0;
    red[g][1][lane] = a1;
    __syncthreads();

    if (g < 2) {   // wave 0 -> alpha, wave 1 -> beta
        float s = red[0][g][lane] + red[1][g][lane] + red[2][g][lane] + red[3][g][lane];
        s += bias[g];
        float r_ = MAXR * tanhf(s);
        (g == 0 ? alpha : beta)[row * 64 + lane] = r_;
    }
}

// ---------------- Kernel 2: per-pixel pairwise soft-abs + softmax + weighted sum
// Block = 256 = 4 waves, 16 pixels/block (one per wave x 4). Lane = channel j.
// x tile staged TRANSPOSED: xst[pixel][channel] so the i-scan is a same-address
// float4 broadcast read (conflict-free) instead of 64 shuffles.
__global__ __launch_bounds__(256) void dsf_main(const float* __restrict__ x,
                                                const float* __restrict__ alpha_g,
                                                const float* __restrict__ beta_g,
                                                float* __restrict__ out) {
    __shared__ float xst[16 * 68];      // [wl][c], stride 68 keeps rows 16B-aligned
    int p0 = blockIdx.x * 16;           // first pixel (same b,h row)
    int b = p0 >> 12;
    const float* xb = x + b * 262144 + (p0 & 4095);
    int tid = threadIdx.x, lane = tid & 63, wave = tid >> 6;

    for (int e = tid; e < 1024; e += 256) {
        int c = e >> 4, wl = e & 15;
        xst[wl * 68 + c] = xb[c * 4096 + wl];
    }
    __syncthreads();

    for (int k = 0; k < 4; ++k) {
        int wl = wave * 4 + k;
        int p = p0 + wl;
        float al = alpha_g[p];
        float be = beta_g[p];
        float aa = fabsf(al);
        float n2aa = -2.0f * aa;        // tanh(z)= (1-e^-2z)/(1+e^-2z), z=aa*|d| (clip moot: tanh sat)
        const float* xr = xst + wl * 68;
        float xj = xr[lane];            // x[b, lane, h, w]

        float A = 0.0f;
        #pragma unroll
        for (int ii = 0; ii < 64; ii += 4) {
            float4 xi4 = *(const float4*)(xr + ii);   // broadcast: all lanes same addr
            #pragma unroll
            for (int u = 0; u < 4; ++u) {
                float xi = (u == 0) ? xi4.x : (u == 1) ? xi4.y : (u == 2) ? xi4.z : xi4.w;
                float dd = fmaf(be, xi, -xj);
                float ad = fabsf(dd);
                float e2 = __expf(n2aa * ad);          // underflows to 0 for big z: t->1
                float t  = (1.0f - e2) * __builtin_amdgcn_rcpf(1.0f + e2);
                A = fmaf(ad, t, A);
            }
        }

        // logits: g_j = max(-A*|alpha|/64, -100)  (sign(alpha) cancels exactly)
        float gl = fmaxf(-A * aa * (1.0f / 64.0f), -MAXR);

        float gm = gl;
        #pragma unroll
        for (int off = 32; off; off >>= 1) gm = fmaxf(gm, __shfl_xor(gm, off, 64));
        float ew  = __expf(gl - gm);
        float den = ew, num = xj * ew;
        #pragma unroll
        for (int off = 32; off; off >>= 1) {
            den += __shfl_xor(den, off, 64);
            num += __shfl_xor(num, off, 64);
        }
        if (lane == 0) out[p] = num / den;
    }
}

extern "C" void kernel_launch(void* const* d_in, const int* in_sizes, int n_in,
                              void* d_out, int out_size, void* d_ws, size_t ws_size,
                              hipStream_t stream) {
    const float* x      = (const float*)d_in[0];   // (4,64,64,64)
    const float* conv_w = (const float*)d_in[1];   // (2,64,3,3)
    const float* conv_b = (const float*)d_in[2];   // (2,)
    float* out   = (float*)d_out;                  // (4,1,64,64)
    float* alpha = (float*)d_ws;                   // 16384 floats
    float* beta  = alpha + 16384;

    conv_ab<<<256, 256, 0, stream>>>(x, conv_w, conv_b, alpha, beta);
    dsf_main<<<1024, 256, 0, stream>>>(x, alpha, beta, out);
}

// Round 3
// 88.254 us; speedup vs baseline: 1.9553x; 1.0827x over previous
//
#include <hip/hip_runtime.h>
#include <math.h>

#define MAXR 100.0f
// Fixed shapes: B=4, C=64, H=64, W=64; conv: (2,64,3,3) OIHW, SAME, stride 1.

// Fully fused: conv(3x3,64->2) + 100*tanh -> (alpha,beta) per pixel, then the
// per-pixel 64x64 channel-pairwise soft-abs reduction + softmax + weighted sum.
// Grid = 1024 blocks, one per 16-pixel row segment (same b,h). Block = 4 waves;
// each wave owns 4 pixels; lane = channel.
__global__ __launch_bounds__(256) void dsf_fused(const float* __restrict__ x,
                                                 const float* __restrict__ wg,
                                                 const float* __restrict__ bias,
                                                 float* __restrict__ out) {
    __shared__ float xs[64 * 3 * 18];   // [c][r][wt], wt -> global w = w0-1+wt; 13.5 KB
    __shared__ float xst[16 * 68];      // [pixel][c] transposed center row; 4.25 KB

    const int tid  = threadIdx.x;
    const int lane = tid & 63;
    const int wave = tid >> 6;

    const int p0 = blockIdx.x * 16;     // first pixel: b*4096 + h*64 + w0
    const int b  = p0 >> 12;
    const int h  = (p0 >> 6) & 63;
    const int w0 = p0 & 63;             // 0,16,32,48

    // ---- per-lane conv weights (channel = lane), 9 taps x 2 outputs ----
    float w0r[9], w1r[9];
    #pragma unroll
    for (int k = 0; k < 9; ++k) {
        w0r[k] = wg[lane * 9 + k];
        w1r[k] = wg[576 + lane * 9 + k];
    }
    const float b0 = bias[0], b1 = bias[1];

    // ---- stage x[b, :, h-1:h+2, w0-1:w0+16] into xs (zero-padded), and the
    //      transposed center row into xst ----
    const float* xbase = x + b * 262144;
    for (int e = tid; e < 3456; e += 256) {       // layout matches xs flat index
        int c   = e / 54;
        int rem = e - c * 54;
        int r   = rem / 18;
        int wt  = rem - r * 18;
        int hh  = h + r - 1;
        int ww  = w0 - 1 + wt;
        float v = 0.f;
        if (hh >= 0 && hh < 64 && ww >= 0 && ww < 64)
            v = xbase[c * 4096 + hh * 64 + ww];
        xs[e] = v;
        if (r == 1 && wt >= 1 && wt <= 16) xst[(wt - 1) * 68 + c] = v;
    }
    __syncthreads();

    const float* xsl = xs + lane * 54;            // this lane's channel slab

    for (int k = 0; k < 4; ++k) {
        const int wl = wave * 4 + k;              // pixel index within tile
        const int p  = p0 + wl;

        // ---- conv for this pixel: lane sums its channel's 9 taps ----
        float a0 = 0.f, a1 = 0.f;
        #pragma unroll
        for (int r = 0; r < 3; ++r) {
            #pragma unroll
            for (int t = 0; t < 3; ++t) {
                float xv = xsl[r * 18 + wl + t];  // wt = (wl+1) + (t-1)
                a0 = fmaf(xv, w0r[r * 3 + t], a0);
                a1 = fmaf(xv, w1r[r * 3 + t], a1);
            }
        }
        #pragma unroll
        for (int off = 32; off; off >>= 1) {      // all-lanes butterfly sum
            a0 += __shfl_xor(a0, off, 64);
            a1 += __shfl_xor(a1, off, 64);
        }
        const float al = MAXR * tanhf(a0 + b0);   // alpha (uniform across wave)
        const float be = MAXR * tanhf(a1 + b1);   // beta
        const float aa = fabsf(al);
        const float n2aa = -2.0f * aa;            // tanh(z)=(1-e^-2z)/(1+e^-2z), z=aa*|d|

        const float* xr = xst + wl * 68;
        const float xj = xr[lane];                // x[b, lane, h, w]

        // ---- pairwise scan: A_j = sum_i |be*x_i - x_j| * tanh(aa*|...|) ----
        float A = 0.0f;
        #pragma unroll
        for (int ii = 0; ii < 64; ii += 4) {
            float4 xi4 = *(const float4*)(xr + ii);   // same-addr broadcast read
            #pragma unroll
            for (int u = 0; u < 4; ++u) {
                float xi = (u == 0) ? xi4.x : (u == 1) ? xi4.y : (u == 2) ? xi4.z : xi4.w;
                float dd = fmaf(be, xi, -xj);
                float ad = fabsf(dd);
                float e2 = __expf(n2aa * ad);         // underflow->0 when saturated
                float t  = (1.0f - e2) * __builtin_amdgcn_rcpf(1.0f + e2);
                A = fmaf(ad, t, A);
            }
        }

        // logits: g_j = max(-A*|alpha|/64, -100)   (sign(alpha) cancels exactly)
        float gl = fmaxf(-A * aa * (1.0f / 64.0f), -MAXR);

        float gm = gl;
        #pragma unroll
        for (int off = 32; off; off >>= 1) gm = fmaxf(gm, __shfl_xor(gm, off, 64));
        float ew  = __expf(gl - gm);
        float den = ew, num = xj * ew;
        #pragma unroll
        for (int off = 32; off; off >>= 1) {
            den += __shfl_xor(den, off, 64);
            num += __shfl_xor(num, off, 64);
        }
        if (lane == 0) out[p] = num / den;
    }
}

extern "C" void kernel_launch(void* const* d_in, const int* in_sizes, int n_in,
                              void* d_out, int out_size, void* d_ws, size_t ws_size,
                              hipStream_t stream) {
    const float* x      = (const float*)d_in[0];   // (4,64,64,64)
    const float* conv_w = (const float*)d_in[1];   // (2,64,3,3)
    const float* conv_b = (const float*)d_in[2];   // (2,)
    float* out = (float*)d_out;                    // (4,1,64,64)
    (void)d_ws; (void)ws_size;

    dsf_fused<<<1024, 256, 0, stream>>>(x, conv_w, conv_b, out);
}

// Round 4
// 85.639 us; speedup vs baseline: 2.0151x; 1.0305x over previous
//
#include <hip/hip_runtime.h>
#include <math.h>

#define MAXR 100.0f
// Fixed shapes: B=4, C=64, H=64, W=64; conv (2,64,3,3) OIHW, SAME.

__device__ __forceinline__ float tanh_fast(float s) {
    // tanh(s) = sign(s) * (1 - e^-2|s|)/(1 + e^-2|s|); abs err ~1e-7, fine vs 3.9e-2 tol
    float as = fabsf(s);
    float e2 = __expf(-2.0f * as);
    float t  = (1.0f - e2) * __builtin_amdgcn_rcpf(1.0f + e2);
    return copysignf(t, s);
}

// Fully fused, latency-optimized: grid 4096 blocks x 256 threads (4 waves).
// Block = 4 consecutive pixels (same b,h); ONE pixel per wave; lane = channel.
// __launch_bounds__(256,8): target 8 waves/SIMD (32/CU) to hide exp/rcp/LDS latency.
__global__ __launch_bounds__(256, 8) void dsf_fused(const float* __restrict__ x,
                                                    const float* __restrict__ wg,
                                                    const float* __restrict__ bias,
                                                    float* __restrict__ out) {
    __shared__ float xs[64 * 19];   // [c][r*6+wt], wt in 0..5; stride 19 (gcd(19,32)=1)
    __shared__ float wl[1152];      // conv weights
    __shared__ float xst[4 * 68];   // [pixel][c] transposed center row

    const int tid  = threadIdx.x;
    const int lane = tid & 63;
    const int wave = tid >> 6;

    const int p0 = blockIdx.x * 4;  // b*4096 + h*64 + w0, w0 multiple of 4
    const int b  = p0 >> 12;
    const int h  = (p0 >> 6) & 63;
    const int w0 = p0 & 63;

    for (int e = tid; e < 1152; e += 256) wl[e] = wg[e];

    // stage x[b, :, h-1:h+2, w0-1:w0+4] zero-padded; transposed center -> xst
    const float* xbase = x + b * 262144;
    for (int e = tid; e < 1152; e += 256) {
        int c   = e / 18;
        int rem = e - c * 18;
        int r   = rem / 6;
        int wt  = rem - r * 6;
        int hh  = h + r - 1;
        int ww  = w0 - 1 + wt;
        float v = 0.f;
        if (hh >= 0 && hh < 64 && ww >= 0 && ww < 64)
            v = xbase[c * 4096 + hh * 64 + ww];
        xs[c * 19 + rem] = v;
        if (r == 1 && wt >= 1 && wt <= 4) xst[(wt - 1) * 68 + c] = v;
    }
    __syncthreads();

    const int p = p0 + wave;        // this wave's pixel

    // ---- conv: lane = channel, 9 taps x 2 outputs, then all-lane butterfly ----
    const float* xc  = xs + lane * 19;
    const float* wle = wl + lane * 9;
    float a0 = 0.f, a1 = 0.f;
    #pragma unroll
    for (int r = 0; r < 3; ++r) {
        #pragma unroll
        for (int t = 0; t < 3; ++t) {
            float xv = xc[r * 6 + wave + t];    // window ww = (w0+wave) + (t-1)
            a0 = fmaf(xv, wle[r * 3 + t], a0);
            a1 = fmaf(xv, wle[576 + r * 3 + t], a1);
        }
    }
    #pragma unroll
    for (int off = 32; off; off >>= 1) {
        a0 += __shfl_xor(a0, off, 64);
        a1 += __shfl_xor(a1, off, 64);
    }
    const float al = MAXR * tanh_fast(a0 + bias[0]);   // alpha (wave-uniform)
    const float be = MAXR * tanh_fast(a1 + bias[1]);   // beta
    const float aa = fabsf(al);
    const float n2aa = -2.0f * aa;  // tanh(z)=(1-e^-2z)/(1+e^-2z), z=aa*|d|

    // ---- pairwise scan: A_j = sum_i |be*x_i - x_j| * tanh(aa*|...|) ----
    const float* xr = xst + wave * 68;
    const float xj = xr[lane];
    float A = 0.0f;
    #pragma unroll 4
    for (int i = 0; i < 64; ++i) {
        float xi = xr[i];                      // same-addr b32 broadcast (free)
        float dd = fmaf(be, xi, -xj);
        float ad = fabsf(dd);
        float e2 = __expf(n2aa * ad);          // underflow->0 when saturated
        float t  = (1.0f - e2) * __builtin_amdgcn_rcpf(1.0f + e2);
        A = fmaf(ad, t, A);
    }

    // logits: g_j = max(-A*|alpha|/64, -100)   (sign(alpha) cancels exactly)
    float gl = fmaxf(-A * aa * (1.0f / 64.0f), -MAXR);

    float gm = gl;
    #pragma unroll
    for (int off = 32; off; off >>= 1) gm = fmaxf(gm, __shfl_xor(gm, off, 64));
    float ew  = __expf(gl - gm);
    float den = ew, num = xj * ew;
    #pragma unroll
    for (int off = 32; off; off >>= 1) {
        den += __shfl_xor(den, off, 64);
        num += __shfl_xor(num, off, 64);
    }
    if (lane == 0) out[p] = num / den;
}

extern "C" void kernel_launch(void* const* d_in, const int* in_sizes, int n_in,
                              void* d_out, int out_size, void* d_ws, size_t ws_size,
                              hipStream_t stream) {
    const float* x      = (const float*)d_in[0];   // (4,64,64,64)
    const float* conv_w = (const float*)d_in[1];   // (2,64,3,3)
    const float* conv_b = (const float*)d_in[2];   // (2,)
    float* out = (float*)d_out;                    // (4,1,64,64)
    (void)d_ws; (void)ws_size;

    dsf_fused<<<4096, 256, 0, stream>>>(x, conv_w, conv_b, out);
}